// Round 12
// baseline (249.414 us; speedup 1.0000x reference)
//
#include <hip/hip_runtime.h>
#include <hip/hip_bf16.h>
#include <math.h>

#define B_   8
#define H_   16
#define BH_  (B_*H_)
#define LK_  4096
#define D_   128

#define SEG   16
#define KSEG  (LK_/SEG)     // 256 keys per score/context block

typedef __attribute__((ext_vector_type(8))) short bf16x8;
typedef __attribute__((ext_vector_type(4))) float f32x4;
typedef __attribute__((ext_vector_type(4))) unsigned int u32x4;

// ---------------- fast tanh (f32, ~1e-6 abs err) ----------------
__device__ __forceinline__ float fast_tanh(float x) {
    float ax = fabsf(x);
    float e  = __expf(2.0f * ax);
    float r  = 1.0f - __fdividef(2.0f, e + 1.0f);
    return copysignf(r, x);
}

// packed f32x2 -> bf16x2 (RNE), single VALU instr
__device__ __forceinline__ unsigned int cvtpk(float lo, float hi) {
    unsigned int r;
    asm("v_cvt_pk_bf16_f32 %0, %1, %2" : "=v"(r) : "v"(lo), "v"(hi));
    return r;
}

// scalar f32 -> bf16 RNE (pack kernel only)
__device__ __forceinline__ unsigned short cvt_hi(float x) {
    __hip_bfloat16 bh = __float2bfloat16(x);
    return __builtin_bit_cast(unsigned short, bh);
}

// 8-wide hi/lo split via v_cvt_pk_bf16_f32: (kh + kl) == x to ~2^-16 rel
__device__ __forceinline__ void cvt8v(const f32x4 a, const f32x4 b, bf16x8& h, bf16x8& l) {
    unsigned int h0 = cvtpk(a[0], a[1]);
    unsigned int h1 = cvtpk(a[2], a[3]);
    unsigned int h2 = cvtpk(b[0], b[1]);
    unsigned int h3 = cvtpk(b[2], b[3]);
    float l0 = a[0] - __uint_as_float(h0 << 16);
    float l1 = a[1] - __uint_as_float(h0 & 0xFFFF0000u);
    float l2 = a[2] - __uint_as_float(h1 << 16);
    float l3 = a[3] - __uint_as_float(h1 & 0xFFFF0000u);
    float l4 = b[0] - __uint_as_float(h2 << 16);
    float l5 = b[1] - __uint_as_float(h2 & 0xFFFF0000u);
    float l6 = b[2] - __uint_as_float(h3 << 16);
    float l7 = b[3] - __uint_as_float(h3 & 0xFFFF0000u);
    u32x4 hv = {h0, h1, h2, h3};
    u32x4 lv = {cvtpk(l0, l1), cvtpk(l2, l3), cvtpk(l4, l5), cvtpk(l6, l7)};
    h = __builtin_bit_cast(bf16x8, hv);
    l = __builtin_bit_cast(bf16x8, lv);
}

// async global -> LDS, 16 B per lane (lds dest must be wave-uniform base)
__device__ __forceinline__ void gld_lds16(const void* g, void* l) {
    __builtin_amdgcn_global_load_lds(
        (const __attribute__((address_space(1))) unsigned int*)g,
        (__attribute__((address_space(3))) unsigned int*)l,
        16, 0, 0);
}

// ---------------- kernel 0: pack W_pre (hi only) into MFMA fragment order ----
// idx = ((ks*8 + nt)*64 + lane)*8 + j ; k = ks*32 + (lane>>4)*8 + j ; n = nt*16 + (lane&15)
__global__ void pack_kernel(const float* __restrict__ Wpre,
                            unsigned short* __restrict__ Whi) {
    int idx  = blockIdx.x * 256 + threadIdx.x;      // 0..16383
    int j    = idx & 7;
    int lane = (idx >> 3) & 63;
    int nt   = (idx >> 9) & 7;
    int ks   = idx >> 12;
    int k    = ks * 32 + (lane >> 4) * 8 + j;
    int n    = nt * 16 + (lane & 15);
    Whi[idx] = cvt_hi(Wpre[k * D_ + n]);
}

// ---------------- kernel 1: tq[bh][e] = Q[bh]·W_q[:,e] ----------------
__global__ void tq_kernel(const float* __restrict__ Q,
                          const float* __restrict__ Wq,
                          float* __restrict__ tq) {
    int bh = blockIdx.x;
    int e  = threadIdx.x;
    const float* q = Q + bh * D_;
    float acc = 0.0f;
#pragma unroll 8
    for (int d = 0; d < D_; ++d)
        acc = fmaf(q[d], Wq[d * D_ + e], acc);
    tq[bh * D_ + e] = acc;
}

// ---------------- kernel 2: pre^T = W^T·K^T (+b) ; energy partials ------------
// SINGLE-WAVE blocks (64 thr), grid (LK/256, 2 e-halves, BH). NO barriers:
// each wave stages its own 16-key x 128-d tile (8 KB) into a private 4-deep
// LDS ring via global_load_lds and self-paces on its own counted vmcnt.
// K rows staged twice (eh 0/1) — L2 dedups, HBM traffic unchanged.
// In-order vmcnt (stores never force-retired < 4 stages old):
//   prologue 24; s=0:29, 1:34, 2:39, 3..11:44, 12:36, 13:28, 14:20, 15 none.
__global__ void __launch_bounds__(64)
main_kernel(const float* __restrict__ K,
            const unsigned short* __restrict__ Whi,
            const float* __restrict__ bpre,
            const float* __restrict__ Wv,
            const float* __restrict__ tqg,
            float* __restrict__ pre_out,
            float* __restrict__ ep0,
            float* __restrict__ ep1) {
    const int lane = threadIdx.x;        // 0..63
    const int l15  = lane & 15;
    const int lg   = lane >> 4;
    const int eh   = blockIdx.y;         // e half (64 cols)
    const int bh   = blockIdx.z;
    const int kblk = blockIdx.x * 256;

    __shared__ float Klds[4][2048];      // 4 x 8 KB private ring

    const float* Kbh = K + (size_t)bh * LK_ * D_;

    // ---- resident W-hi fragments: this wave's e-half, all ks (64 VGPR)
    bf16x8 wf[4][4];
#pragma unroll
    for (int ks = 0; ks < 4; ++ks)
#pragma unroll
        for (int et = 0; et < 4; ++et)
            wf[ks][et] = *(const bf16x8*)(Whi + (((size_t)ks * 8 + eh * 4 + et) * 64 + lane) * 8);

    // ---- hoisted epilogue constants (per-wave e-range)
    float4 bpv[4], tqv[4], wvv[4];
#pragma unroll
    for (int et = 0; et < 4; ++et) {
        const int e0 = eh * 64 + et * 16 + lg * 4;
        bpv[et] = *(const float4*)(bpre + e0);
        tqv[et] = *(const float4*)(tqg + bh * D_ + e0);
        wvv[et] = *(const float4*)(Wv + e0);
    }

    float* epo = (eh == 0) ? ep0 : ep1;

    // ---- DMA stage of 16-key tile s (8 KB = 8 granules; granule g4:
    // ks2=g4>>1, h2=g4&1; row = s*16 + l15, col = lg*8 + ks2*32 + h2*4)
    auto stageK = [&](int s, int buf) {
#pragma unroll
        for (int g4 = 0; g4 < 8; ++g4) {
            const int ks2 = g4 >> 1, h2 = g4 & 1;
            const int row = kblk + s * 16 + l15;
            const int col = lg * 8 + ks2 * 32 + h2 * 4;
            gld_lds16(Kbh + (size_t)row * D_ + col, &Klds[buf][g4 * 256]);
        }
    };

    stageK(0, 0);
    stageK(1, 1);
    stageK(2, 2);
    stageK(3, 3);
    // need D0 done; ops younger than D0 = D1+D2+D3 = 24
    asm volatile("s_waitcnt vmcnt(24)" ::: "memory");

#pragma unroll
    for (int s = 0; s < 16; ++s) {
        const float* kb = Klds[s & 3];
        f32x4 acc[4];
#pragma unroll
        for (int et = 0; et < 4; ++et)
            acc[et] = (f32x4){0.f, 0.f, 0.f, 0.f};

#pragma unroll
        for (int ks = 0; ks < 4; ++ks) {
            f32x4 p0 = *(const f32x4*)(kb + (ks * 2) * 256 + lane * 4);
            f32x4 p1 = *(const f32x4*)(kb + (ks * 2 + 1) * 256 + lane * 4);
            bf16x8 kh, kl;
            cvt8v(p0, p1, kh, kl);
#pragma unroll
            for (int et = 0; et < 4; ++et) {
                acc[et] = __builtin_amdgcn_mfma_f32_16x16x32_bf16(wf[ks][et], kh, acc[et], 0, 0, 0);
                acc[et] = __builtin_amdgcn_mfma_f32_16x16x32_bf16(wf[ks][et], kl, acc[et], 0, 0, 0);
            }
        }

        // refill this buffer for stage s+4 (issued AFTER the reads above)
        if (s + 4 < 16) stageK(s + 4, (s + 4) & 3);

        // ---- epilogue: pre store (plain f32x4, 4x) + energy partial (1x)
        const int key = kblk + s * 16 + l15;
        float* pb = pre_out + (size_t)bh * LK_ * D_ + (size_t)key * D_;
        float ep = 0.0f;
#pragma unroll
        for (int et = 0; et < 4; ++et) {
            const int e0 = eh * 64 + et * 16 + lg * 4;
            f32x4 a = acc[et];
            f32x4 v;
            v[0] = a[0] + bpv[et].x;
            v[1] = a[1] + bpv[et].y;
            v[2] = a[2] + bpv[et].z;
            v[3] = a[3] + bpv[et].w;
            *(f32x4*)(pb + e0) = v;
            ep = fmaf(fast_tanh(v[0] + tqv[et].x), wvv[et].x, ep);
            ep = fmaf(fast_tanh(v[1] + tqv[et].y), wvv[et].y, ep);
            ep = fmaf(fast_tanh(v[2] + tqv[et].z), wvv[et].z, ep);
            ep = fmaf(fast_tanh(v[3] + tqv[et].w), wvv[et].w, ep);
        }
        ep += __shfl_xor(ep, 16, 64);
        ep += __shfl_xor(ep, 32, 64);
        // unconditional: the 4 lg-lanes write the identical value to the same addr
        epo[(size_t)bh * LK_ + key] = ep;

        // per-wave counted wait: guarantee D(s+1) done, never force young stores
        if (s == 0)
            asm volatile("s_waitcnt vmcnt(29)" ::: "memory");
        else if (s == 1)
            asm volatile("s_waitcnt vmcnt(34)" ::: "memory");
        else if (s == 2)
            asm volatile("s_waitcnt vmcnt(39)" ::: "memory");
        else if (s <= 11)
            asm volatile("s_waitcnt vmcnt(44)" ::: "memory");
        else if (s == 12)
            asm volatile("s_waitcnt vmcnt(36)" ::: "memory");
        else if (s == 13)
            asm volatile("s_waitcnt vmcnt(28)" ::: "memory");
        else if (s == 14)
            asm volatile("s_waitcnt vmcnt(20)" ::: "memory");
        // s == 15: no wait; kernel end drains
    }
}

// ---------------- kernel 3a: per-(b,h) masked max & sum(exp) ----------------
__global__ void ml_kernel(const float* __restrict__ ep0,
                          const float* __restrict__ ep1,
                          const int* __restrict__ mask,
                          float* __restrict__ ml) {
    const int bh = blockIdx.x;
    const int t  = threadIdx.x;
    const float* e0 = ep0 + (size_t)bh * LK_;
    const float* e1 = ep1 + (size_t)bh * LK_;
    const int*   m  = mask + (size_t)bh * LK_;

    float mx = -1e30f;
    for (int k = t; k < LK_; k += 256) {
        float v = m[k] ? -1.0e6f : (e0[k] + e1[k]);
        mx = fmaxf(mx, v);
    }
#pragma unroll
    for (int off = 32; off > 0; off >>= 1)
        mx = fmaxf(mx, __shfl_xor(mx, off, 64));
    __shared__ float wmax[4];
    if ((t & 63) == 0) wmax[t >> 6] = mx;
    __syncthreads();
    mx = fmaxf(fmaxf(wmax[0], wmax[1]), fmaxf(wmax[2], wmax[3]));

    float sum = 0.0f;
    for (int k = t; k < LK_; k += 256) {
        float v = m[k] ? -1.0e6f : (e0[k] + e1[k]);
        sum += __expf(v - mx);
    }
#pragma unroll
    for (int off = 32; off > 0; off >>= 1)
        sum += __shfl_xor(sum, off, 64);
    __shared__ float wsum[4];
    if ((t & 63) == 0) wsum[t >> 6] = sum;
    __syncthreads();
    if (t == 0) {
        ml[bh * 2]     = mx;
        ml[bh * 2 + 1] = wsum[0] + wsum[1] + wsum[2] + wsum[3];
    }
}

// ---------------- kernel 3b: score + partial context ----------------
// grid: (SEG, BH), block 256. KSEG=256: one score per thread, float4 V loads.
// Reads energy = ep0 + ep1; overwrites ep0 (score region) with final score.
__global__ void score_ctx_kernel(const float* __restrict__ ep1,
                                 const int* __restrict__ mask,
                                 const float* __restrict__ V,
                                 const float* __restrict__ ml,
                                 float* __restrict__ score_out,
                                 float* __restrict__ part) {
    const int seg = blockIdx.x;
    const int bh  = blockIdx.y;
    const int t   = threadIdx.x;
    const int k0  = seg * KSEG;

    __shared__ float sc[KSEG];
    __shared__ float pl[8][136];

    const float mx  = ml[bh * 2];
    const float inv = 1.0f / ml[bh * 2 + 1];

    {
        const size_t gi = (size_t)bh * LK_ + k0 + t;
        float v = mask[gi] ? -1.0e6f : (score_out[gi] + ep1[gi]);
        float s = __expf(v - mx) * inv;
        sc[t] = s;
        score_out[gi] = s;
    }
    __syncthreads();

    const int d4 = t & 31;           // float4 column
    const int g  = t >> 5;           // k-group 0..7
    const float* Vb = V + ((size_t)bh * LK_ + k0) * D_ + d4 * 4;
    float4 a = make_float4(0.f, 0.f, 0.f, 0.f);
#pragma unroll 4
    for (int kk = g; kk < KSEG; kk += 8) {
        float4 vv = *(const float4*)(Vb + (size_t)kk * D_);
        float s = sc[kk];
        a.x = fmaf(s, vv.x, a.x);
        a.y = fmaf(s, vv.y, a.y);
        a.z = fmaf(s, vv.z, a.z);
        a.w = fmaf(s, vv.w, a.w);
    }
    *(float4*)&pl[g][d4 * 4] = a;
    __syncthreads();

    if (t < 128) {
        float s = 0.0f;
#pragma unroll
        for (int gg = 0; gg < 8; ++gg)
            s += pl[gg][t];
        part[((size_t)bh * SEG + seg) * D_ + t] = s;
    }
}

// ---------------- kernel 3c: combine partial contexts ----------------
__global__ void combine_kernel(const float* __restrict__ part,
                               float* __restrict__ ctx) {
    const int bh = blockIdx.x;
    const int d  = threadIdx.x;
    float s = 0.0f;
#pragma unroll
    for (int g = 0; g < SEG; ++g)
        s += part[((size_t)bh * SEG + g) * D_ + d];
    ctx[bh * D_ + d] = s;
}

// ---------------- launch ----------------
extern "C" void kernel_launch(void* const* d_in, const int* in_sizes, int n_in,
                              void* d_out, int out_size, void* d_ws, size_t ws_size,
                              hipStream_t stream) {
    const float* Q    = (const float*)d_in[0];
    const float* K    = (const float*)d_in[1];
    const float* V    = (const float*)d_in[2];
    const int*   mask = (const int*)  d_in[3];
    // d_in[4] = scale (unused by reference)
    const float* Wpre = (const float*)d_in[5];
    const float* bpre = (const float*)d_in[6];
    const float* Wq   = (const float*)d_in[7];
    const float* Wv   = (const float*)d_in[8];

    float* out   = (float*)d_out;
    float* ctx   = out;                           // [BH][D]
    float* score = out + (size_t)BH_ * D_;        // [BH][LK] — holds ep0 then score
    float* pre   = score + (size_t)BH_ * LK_;     // [BH][LK][D]

    float* w    = (float*)d_ws;
    float* tq   = w;                              // BH*D floats
    float* ml   = tq + (size_t)BH_ * D_;          // BH*2
    float* part = ml + 2 * BH_;                   // BH*SEG*D
    unsigned short* Whi = (unsigned short*)(part + (size_t)BH_ * SEG * D_); // 16384
    float* ep1  = (float*)(Whi + 16384);          // BH*LK (2 MB)

    hipLaunchKernelGGL(pack_kernel, dim3(64), dim3(256), 0, stream, Wpre, Whi);
    hipLaunchKernelGGL(tq_kernel, dim3(BH_), dim3(D_), 0, stream, Q, Wq, tq);
    hipLaunchKernelGGL(main_kernel, dim3(LK_ / 256, 2, BH_), dim3(64), 0, stream,
                       K, Whi, bpre, Wv, tq, pre, score, ep1);
    hipLaunchKernelGGL(ml_kernel, dim3(BH_), dim3(256), 0, stream, score, ep1, mask, ml);
    hipLaunchKernelGGL(score_ctx_kernel, dim3(SEG, BH_), dim3(256), 0, stream,
                       ep1, mask, V, ml, score, part);
    hipLaunchKernelGGL(combine_kernel, dim3(BH_), dim3(D_), 0, stream, part, ctx);
}

// Round 14
// 202.518 us; speedup vs baseline: 1.2316x; 1.2316x over previous
//
#include <hip/hip_runtime.h>
#include <hip/hip_bf16.h>
#include <math.h>

#define B_   8
#define H_   16
#define BH_  (B_*H_)
#define LK_  4096
#define D_   128

#define SEG   16
#define KSEG  (LK_/SEG)     // 256 keys per score/context block

typedef __attribute__((ext_vector_type(8))) short bf16x8;
typedef __attribute__((ext_vector_type(4))) float f32x4;
typedef __attribute__((ext_vector_type(4))) unsigned int u32x4;

// ---------------- fast tanh (f32, ~1e-6 abs err) ----------------
__device__ __forceinline__ float fast_tanh(float x) {
    float ax = fabsf(x);
    float e  = __expf(2.0f * ax);
    float r  = 1.0f - __fdividef(2.0f, e + 1.0f);
    return copysignf(r, x);
}

// packed f32x2 -> bf16x2 (RNE), single VALU instr
__device__ __forceinline__ unsigned int cvtpk(float lo, float hi) {
    unsigned int r;
    asm("v_cvt_pk_bf16_f32 %0, %1, %2" : "=v"(r) : "v"(lo), "v"(hi));
    return r;
}

// scalar f32 -> bf16 RNE (pack kernel only)
__device__ __forceinline__ unsigned short cvt_hi(float x) {
    __hip_bfloat16 bh = __float2bfloat16(x);
    return __builtin_bit_cast(unsigned short, bh);
}

// 8-wide hi/lo split via v_cvt_pk_bf16_f32: (kh + kl) == x to ~2^-16 rel
__device__ __forceinline__ void cvt8v(const f32x4 a, const f32x4 b, bf16x8& h, bf16x8& l) {
    unsigned int h0 = cvtpk(a[0], a[1]);
    unsigned int h1 = cvtpk(a[2], a[3]);
    unsigned int h2 = cvtpk(b[0], b[1]);
    unsigned int h3 = cvtpk(b[2], b[3]);
    float l0 = a[0] - __uint_as_float(h0 << 16);
    float l1 = a[1] - __uint_as_float(h0 & 0xFFFF0000u);
    float l2 = a[2] - __uint_as_float(h1 << 16);
    float l3 = a[3] - __uint_as_float(h1 & 0xFFFF0000u);
    float l4 = b[0] - __uint_as_float(h2 << 16);
    float l5 = b[1] - __uint_as_float(h2 & 0xFFFF0000u);
    float l6 = b[2] - __uint_as_float(h3 << 16);
    float l7 = b[3] - __uint_as_float(h3 & 0xFFFF0000u);
    u32x4 hv = {h0, h1, h2, h3};
    u32x4 lv = {cvtpk(l0, l1), cvtpk(l2, l3), cvtpk(l4, l5), cvtpk(l6, l7)};
    h = __builtin_bit_cast(bf16x8, hv);
    l = __builtin_bit_cast(bf16x8, lv);
}

// async global -> LDS, 16 B per lane (lds dest is wave-uniform base + lane*16)
__device__ __forceinline__ void gld_lds16(const void* g, void* l) {
    __builtin_amdgcn_global_load_lds(
        (const __attribute__((address_space(1))) unsigned int*)g,
        (__attribute__((address_space(3))) unsigned int*)l,
        16, 0, 0);
}

// ---------------- kernel 0: pack W_pre (hi only) into MFMA fragment order ----
// idx = ((ks*8 + nt)*64 + lane)*8 + j ; k = ks*32 + (lane>>4)*8 + j ; n = nt*16 + (lane&15)
__global__ void pack_kernel(const float* __restrict__ Wpre,
                            unsigned short* __restrict__ Whi) {
    int idx  = blockIdx.x * 256 + threadIdx.x;      // 0..16383
    int j    = idx & 7;
    int lane = (idx >> 3) & 63;
    int nt   = (idx >> 9) & 7;
    int ks   = idx >> 12;
    int k    = ks * 32 + (lane >> 4) * 8 + j;
    int n    = nt * 16 + (lane & 15);
    Whi[idx] = cvt_hi(Wpre[k * D_ + n]);
}

// ---------------- kernel 1: tq[bh][e] = Q[bh]·W_q[:,e] ----------------
__global__ void tq_kernel(const float* __restrict__ Q,
                          const float* __restrict__ Wq,
                          float* __restrict__ tq) {
    int bh = blockIdx.x;
    int e  = threadIdx.x;
    const float* q = Q + bh * D_;
    float acc = 0.0f;
#pragma unroll 8
    for (int d = 0; d < D_; ++d)
        acc = fmaf(q[d], Wq[d * D_ + e], acc);
    tq[bh * D_ + e] = acc;
}

// ---------------- kernel 2: pre^T = W^T·K^T (+b) ; energy partials ------------
// grid (LK/256, BH), block 256 = 4 waves = (2 key-groups) x (2 e-halves).
// K staged global->LDS via global_load_lds DMA, 3-deep rotation (48 KB),
// issued 2 stages ahead. Counted waits per IN-ORDER vmcnt retirement:
// N = ops younger than D(s+1) = st(s-1)5 + D(s+2)4 + st(s)5 = 14 steady
// (9 at s=0, 10 at s=6, none at s=7) -> stores get a ~2-stage retire window
// and are never force-retired young. pre stores are NT (bypass L2 — pre is
// never re-read; keeps L2 clean for K/ep/V in the downstream kernels);
// ep stores are PLAIN (re-read by ml_kernel immediately -> want L2 ack+hit).
__global__ void __launch_bounds__(256, 3)
main_kernel(const float* __restrict__ K,
            const unsigned short* __restrict__ Whi,
            const float* __restrict__ bpre,
            const float* __restrict__ Wv,
            const float* __restrict__ tqg,
            float* __restrict__ pre_out,
            float* __restrict__ ep0,
            float* __restrict__ ep1) {
    const int t    = threadIdx.x;
    const int lane = t & 63;
    const int wv_  = t >> 6;
    const int kg   = wv_ & 1;            // key group (16 keys within 32-key stage)
    const int eh   = wv_ >> 1;           // e half (64 cols)
    const int l15  = lane & 15;
    const int lg   = lane >> 4;
    const int bh   = blockIdx.y;
    const int kblk = blockIdx.x * 256;

    __shared__ float Klds[3][4096];      // 3 x 16 KB rotating staging buffers

    const float* Kbh = K + (size_t)bh * LK_ * D_;

    // ---- resident W-hi fragments: this wave's e-half, all ks (64 VGPR)
    bf16x8 wf[4][4];
#pragma unroll
    for (int ks = 0; ks < 4; ++ks)
#pragma unroll
        for (int et = 0; et < 4; ++et)
            wf[ks][et] = *(const bf16x8*)(Whi + (((size_t)ks * 8 + eh * 4 + et) * 64 + lane) * 8);

    // ---- hoisted epilogue constants (per-wave e-range)
    float4 bpv[4], tqv[4], wvv[4];
#pragma unroll
    for (int et = 0; et < 4; ++et) {
        const int e0 = eh * 64 + et * 16 + lg * 4;
        bpv[et] = *(const float4*)(bpre + e0);
        tqv[et] = *(const float4*)(tqg + bh * D_ + e0);
        wvv[et] = *(const float4*)(Wv + e0);
    }

    float* epo = (eh == 0) ? ep0 : ep1;

    // ---- DMA stage of 32-key tile s into buffer buf (4 gld_lds16 per wave)
    auto stageK = [&](int s, int buf) {
#pragma unroll
        for (int i = 0; i < 4; ++i) {
            const int g4  = wv_ * 4 + i;
            const int kg2 = g4 >> 3, ks2 = (g4 >> 1) & 3, h2 = g4 & 1;
            const int row = kblk + s * 32 + kg2 * 16 + l15;
            const int col = lg * 8 + ks2 * 32 + h2 * 4;
            gld_lds16(Kbh + (size_t)row * D_ + col, &Klds[buf][g4 * 256]);
        }
    };

    stageK(0, 0);
    stageK(1, 1);
    // want D0 done; ops younger than D0 = D1(4) -> vmcnt(4)
    asm volatile("s_waitcnt vmcnt(4)\n\ts_barrier" ::: "memory");

#pragma unroll
    for (int s = 0; s < 8; ++s) {
        if (s + 2 < 8) stageK(s + 2, (s + 2) % 3);   // 2 stages ahead

        const float* kb = Klds[s % 3];
        f32x4 acc[4];
#pragma unroll
        for (int et = 0; et < 4; ++et)
            acc[et] = (f32x4){0.f, 0.f, 0.f, 0.f};

#pragma unroll
        for (int ks = 0; ks < 4; ++ks) {
            const int gbase = ((kg * 4 + ks) * 2) * 256 + lane * 4;   // h=0 granule
            f32x4 p0 = *(const f32x4*)(kb + gbase);
            f32x4 p1 = *(const f32x4*)(kb + gbase + 256);             // h=1 granule
            bf16x8 kh, kl;
            cvt8v(p0, p1, kh, kl);
#pragma unroll
            for (int et = 0; et < 4; ++et) {
                acc[et] = __builtin_amdgcn_mfma_f32_16x16x32_bf16(wf[ks][et], kh, acc[et], 0, 0, 0);
                acc[et] = __builtin_amdgcn_mfma_f32_16x16x32_bf16(wf[ks][et], kl, acc[et], 0, 0, 0);
            }
        }

        // ---- epilogue: pre store (NT f32x4, 4x) + energy partial (plain, 1x)
        const int key = kblk + s * 32 + kg * 16 + l15;
        float* pb = pre_out + (size_t)bh * LK_ * D_ + (size_t)key * D_;
        float ep = 0.0f;
#pragma unroll
        for (int et = 0; et < 4; ++et) {
            const int e0 = eh * 64 + et * 16 + lg * 4;
            f32x4 a = acc[et];
            f32x4 v;
            v[0] = a[0] + bpv[et].x;
            v[1] = a[1] + bpv[et].y;
            v[2] = a[2] + bpv[et].z;
            v[3] = a[3] + bpv[et].w;
            __builtin_nontemporal_store(v, (f32x4*)(pb + e0));
            ep = fmaf(fast_tanh(v[0] + tqv[et].x), wvv[et].x, ep);
            ep = fmaf(fast_tanh(v[1] + tqv[et].y), wvv[et].y, ep);
            ep = fmaf(fast_tanh(v[2] + tqv[et].z), wvv[et].z, ep);
            ep = fmaf(fast_tanh(v[3] + tqv[et].w), wvv[et].w, ep);
        }
        ep += __shfl_xor(ep, 16, 64);
        ep += __shfl_xor(ep, 32, 64);
        // unconditional: the 4 lg-lanes write the identical value to the same addr
        epo[(size_t)bh * LK_ + key] = ep;

        // counted wait: guarantee D(s+1) done without forcing young store acks
        if (s == 0)
            asm volatile("s_waitcnt vmcnt(9)\n\ts_barrier" ::: "memory");
        else if (s < 6)
            asm volatile("s_waitcnt vmcnt(14)\n\ts_barrier" ::: "memory");
        else if (s == 6)
            asm volatile("s_waitcnt vmcnt(10)\n\ts_barrier" ::: "memory");
        // s == 7: no wait; kernel end drains
    }
}

// ---------------- kernel 3a: per-(b,h) masked max & sum(exp) ----------------
__global__ void ml_kernel(const float* __restrict__ ep0,
                          const float* __restrict__ ep1,
                          const int* __restrict__ mask,
                          float* __restrict__ ml) {
    const int bh = blockIdx.x;
    const int t  = threadIdx.x;
    const float* e0 = ep0 + (size_t)bh * LK_;
    const float* e1 = ep1 + (size_t)bh * LK_;
    const int*   m  = mask + (size_t)bh * LK_;

    float mx = -1e30f;
    for (int k = t; k < LK_; k += 256) {
        float v = m[k] ? -1.0e6f : (e0[k] + e1[k]);
        mx = fmaxf(mx, v);
    }
#pragma unroll
    for (int off = 32; off > 0; off >>= 1)
        mx = fmaxf(mx, __shfl_xor(mx, off, 64));
    __shared__ float wmax[4];
    if ((t & 63) == 0) wmax[t >> 6] = mx;
    __syncthreads();
    mx = fmaxf(fmaxf(wmax[0], wmax[1]), fmaxf(wmax[2], wmax[3]));

    float sum = 0.0f;
    for (int k = t; k < LK_; k += 256) {
        float v = m[k] ? -1.0e6f : (e0[k] + e1[k]);
        sum += __expf(v - mx);
    }
#pragma unroll
    for (int off = 32; off > 0; off >>= 1)
        sum += __shfl_xor(sum, off, 64);
    __shared__ float wsum[4];
    if ((t & 63) == 0) wsum[t >> 6] = sum;
    __syncthreads();
    if (t == 0) {
        ml[bh * 2]     = mx;
        ml[bh * 2 + 1] = wsum[0] + wsum[1] + wsum[2] + wsum[3];
    }
}

// ---------------- kernel 3b: score + partial context ----------------
// grid: (SEG, BH), block 256. KSEG=256: one score per thread, float4 V loads.
// Reads energy = ep0 + ep1; overwrites ep0 (score region) with final score.
__global__ void score_ctx_kernel(const float* __restrict__ ep1,
                                 const int* __restrict__ mask,
                                 const float* __restrict__ V,
                                 const float* __restrict__ ml,
                                 float* __restrict__ score_out,
                                 float* __restrict__ part) {
    const int seg = blockIdx.x;
    const int bh  = blockIdx.y;
    const int t   = threadIdx.x;
    const int k0  = seg * KSEG;

    __shared__ float sc[KSEG];
    __shared__ float pl[8][136];

    const float mx  = ml[bh * 2];
    const float inv = 1.0f / ml[bh * 2 + 1];

    {
        const size_t gi = (size_t)bh * LK_ + k0 + t;
        float v = mask[gi] ? -1.0e6f : (score_out[gi] + ep1[gi]);
        float s = __expf(v - mx) * inv;
        sc[t] = s;
        score_out[gi] = s;
    }
    __syncthreads();

    const int d4 = t & 31;           // float4 column
    const int g  = t >> 5;           // k-group 0..7
    const float* Vb = V + ((size_t)bh * LK_ + k0) * D_ + d4 * 4;
    float4 a = make_float4(0.f, 0.f, 0.f, 0.f);
#pragma unroll 4
    for (int kk = g; kk < KSEG; kk += 8) {
        float4 vv = *(const float4*)(Vb + (size_t)kk * D_);
        float s = sc[kk];
        a.x = fmaf(s, vv.x, a.x);
        a.y = fmaf(s, vv.y, a.y);
        a.z = fmaf(s, vv.z, a.z);
        a.w = fmaf(s, vv.w, a.w);
    }
    *(float4*)&pl[g][d4 * 4] = a;
    __syncthreads();

    if (t < 128) {
        float s = 0.0f;
#pragma unroll
        for (int gg = 0; gg < 8; ++gg)
            s += pl[gg][t];
        part[((size_t)bh * SEG + seg) * D_ + t] = s;
    }
}

// ---------------- kernel 3c: combine partial contexts ----------------
__global__ void combine_kernel(const float* __restrict__ part,
                               float* __restrict__ ctx) {
    const int bh = blockIdx.x;
    const int d  = threadIdx.x;
    float s = 0.0f;
#pragma unroll
    for (int g = 0; g < SEG; ++g)
        s += part[((size_t)bh * SEG + g) * D_ + d];
    ctx[bh * D_ + d] = s;
}

// ---------------- launch ----------------
extern "C" void kernel_launch(void* const* d_in, const int* in_sizes, int n_in,
                              void* d_out, int out_size, void* d_ws, size_t ws_size,
                              hipStream_t stream) {
    const float* Q    = (const float*)d_in[0];
    const float* K    = (const float*)d_in[1];
    const float* V    = (const float*)d_in[2];
    const int*   mask = (const int*)  d_in[3];
    // d_in[4] = scale (unused by reference)
    const float* Wpre = (const float*)d_in[5];
    const float* bpre = (const float*)d_in[6];
    const float* Wq   = (const float*)d_in[7];
    const float* Wv   = (const float*)d_in[8];

    float* out   = (float*)d_out;
    float* ctx   = out;                           // [BH][D]
    float* score = out + (size_t)BH_ * D_;        // [BH][LK] — holds ep0 then score
    float* pre   = score + (size_t)BH_ * LK_;     // [BH][LK][D]

    float* w    = (float*)d_ws;
    float* tq   = w;                              // BH*D floats
    float* ml   = tq + (size_t)BH_ * D_;          // BH*2
    float* part = ml + 2 * BH_;                   // BH*SEG*D
    unsigned short* Whi = (unsigned short*)(part + (size_t)BH_ * SEG * D_); // 16384
    float* ep1  = (float*)(Whi + 16384);          // BH*LK (2 MB)

    hipLaunchKernelGGL(pack_kernel, dim3(64), dim3(256), 0, stream, Wpre, Whi);
    hipLaunchKernelGGL(tq_kernel, dim3(BH_), dim3(D_), 0, stream, Q, Wq, tq);
    hipLaunchKernelGGL(main_kernel, dim3(LK_ / 256, BH_), dim3(256), 0, stream,
                       K, Whi, bpre, Wv, tq, pre, score, ep1);
    hipLaunchKernelGGL(ml_kernel, dim3(BH_), dim3(256), 0, stream, score, ep1, mask, ml);
    hipLaunchKernelGGL(score_ctx_kernel, dim3(SEG, BH_), dim3(256), 0, stream,
                       ep1, mask, V, ml, score, part);
    hipLaunchKernelGGL(combine_kernel, dim3(BH_), dim3(D_), 0, stream, part, ctx);
}